// Round 1
// 427.473 us; speedup vs baseline: 1.0045x; 1.0045x over previous
//
#include <hip/hip_runtime.h>

// Nearest-voxel gather: out[i] = f[clip((x[i]+1)/h,0,255) per axis], h=2/255.
// N = 2^24 points, f = 256^3 float32 (67 MB; > 32MB aggregate L2, < 256MB L3).
//
// R2 (4 pts/thread, 48B-lane-stride loads): 197us, FETCH 636MB, WRITE 65MB.
// R3 (16 pts/thread, 192B-lane-stride): 287us REGRESSION — WRITE 164MB (partial
//   -line nontemporal stores), FETCH 751MB. Lesson: per-instruction lane
//   coalescing dominates.
// R4 (LDS-staged x, stride-256 assignment, P=8): 186us/dispatch, FETCH 591MB,
//   Occupancy 60%, VALUBusy 12%. Gather-latency-bound: implied ~100
//   outstanding lines/CU << what resident waves could sustain. LDS caps
//   residency at 6 blocks/CU and __syncthreads() phase-bunches gathers
//   (zero gathers in flight during the staging phase).
// R5: drop LDS + barrier. Stride-256 assignment kept (coalesced 4B/lane
//   stores); x reads become lane-stride-12B dword loads (768B window per
//   instr triple — MSHR merges, FETCH_x stays ~201MB). 40 VGPR, no LDS,
//   __launch_bounds__(256,8) -> 8 blocks/CU = 32 waves, free-running, so
//   gather MLP is continuous instead of phase-bunched.

#define P 8                               // points per thread (8 gathers in flight)
#define BLK 256
#define PTS_PER_BLK (P * BLK)             // 2048 points

__device__ __forceinline__ int vox_idx(float v) {
    // Bit-match reference: f32 IEEE divide by h (no fast-math reciprocal).
    const float h = 2.0f / 255.0f;
    float p = (v + 1.0f) / h;
    p = fminf(fmaxf(p, 0.0f), 255.0f);
    return (int)p;  // p >= 0, truncation == astype(int32)
}

__global__ __launch_bounds__(BLK, 8) void voxel_gather_kernel(
    const float* __restrict__ x, const float* __restrict__ f,
    float* __restrict__ out)
{
    const int tid = threadIdx.x;
    const long long base = (long long)blockIdx.x * PTS_PER_BLK;

    // Phase 1: compute all P voxel indices. Per point: 3 nontemporal dword
    // loads at lane-stride 12B (wave footprint 768B per component — lines
    // fully consumed across the 3 components via L1/MSHR merge).
    int idx[P];
#pragma unroll
    for (int j = 0; j < P; ++j) {
        const long long p = base + tid + BLK * j;
        const float* xp = x + 3 * p;
        float cx = __builtin_nontemporal_load(xp + 0);
        float cy = __builtin_nontemporal_load(xp + 1);
        float cz = __builtin_nontemporal_load(xp + 2);
        idx[j] = (vox_idx(cx) << 16) | (vox_idx(cy) << 8) | vox_idx(cz);
    }

    // Phase 2: 8 independent cached gathers in flight per wave, 32 waves/CU.
    float r[P];
#pragma unroll
    for (int j = 0; j < P; ++j) r[j] = f[idx[j]];

    // Phase 3: coalesced full-line NT stores: 64 lanes x 4B contiguous.
    float* ob = out + base;
#pragma unroll
    for (int j = 0; j < P; ++j)
        __builtin_nontemporal_store(r[j], &ob[tid + BLK * j]);
}

extern "C" void kernel_launch(void* const* d_in, const int* in_sizes, int n_in,
                              void* d_out, int out_size, void* d_ws, size_t ws_size,
                              hipStream_t stream) {
    const float* x = (const float*)d_in[0];  // (N, 3) float32
    const float* f = (const float*)d_in[1];  // (256,256,256) float32
    float* out = (float*)d_out;              // (N,) float32

    int n = in_sizes[0] / 3;                 // 16777216 points
    int nblk = n / PTS_PER_BLK;              // 8192 blocks, no tail (n = 2^24)
    voxel_gather_kernel<<<dim3(nblk), dim3(BLK), 0, stream>>>(x, f, out);
}